// Round 2
// baseline (269.685 us; speedup 1.0000x reference)
//
#include <hip/hip_runtime.h>

// out[i]        = p[i]                      i in [0, SIZE)
// out[SIZE + i] = w[i] * selu(p[i]) + q[i]
//
// Round-4 (resubmit after GPUAcquisitionTimeout in round-1; never measured):
// merge the two dispatches into ONE kernel with a block-level role
// split (even blocks: 2-stream copy; odd blocks: 4-stream selu-residual).
// Rationale:
//  - removes the k1->k2 dispatch barrier (launch gap + k1 tail, ~8-15 us)
//  - copy (1:1 R:W) and selu (3:1 R:W) phases share the memory system
//    concurrently instead of running phase-locked back-to-back
//  - role branch is block-uniform -> no divergence; max 4 streams/thread,
//    so this does NOT recreate the round-3 fused 5-stream regression
//  - p lines fetched by copy block 2k are re-read by selu block 2k+1 at
//    nearly the same time -> L3 (die-level, shared across XCDs) absorbs
//    the second read.
// Kept from round-3 findings: thread-per-float4, no unroll, no nt hints.

typedef float v4f __attribute__((ext_vector_type(4)));

__global__ void __launch_bounds__(256)
fused_roles_kernel(const v4f* __restrict__ x4, const v4f* __restrict__ w4,
                   v4f* __restrict__ out4, int n4) {
    int bid  = blockIdx.x;
    int role = bid & 1;                       // 0: copy half, 1: selu half
    int i    = (bid >> 1) * blockDim.x + threadIdx.x;
    if (i >= n4) return;

    if (role == 0) {
        // out[0:SIZE) = p  (2 streams)
        out4[i] = x4[i];
    } else {
        // out[SIZE:N) = w * selu(p) + q  (4 streams; p likely L3-hit)
        const float scale = 1.0507009873554805f;
        const float alpha = 1.6732632423543773f;

        v4f p = x4[i];
        v4f q = x4[n4 + i];
        v4f w = w4[i];

        v4f r;
#pragma unroll
        for (int c = 0; c < 4; ++c) {
            float pv = p[c];
            float s  = pv > 0.f ? pv : alpha * (__expf(pv) - 1.f);
            r[c] = w[c] * (scale * s) + q[c];
        }
        out4[n4 + i] = r;
    }
}

extern "C" void kernel_launch(void* const* d_in, const int* in_sizes, int n_in,
                              void* d_out, int out_size, void* d_ws, size_t ws_size,
                              hipStream_t stream) {
    const v4f* x4 = (const v4f*)d_in[0];
    const v4f* w4 = (const v4f*)d_in[1];
    v4f* out4 = (v4f*)d_out;

    int size = in_sizes[1];      // SIZE = N/2 = 16777216
    int n4 = size / 4;           // 4194304 float4 per half

    int block = 256;
    int blocks_per_role = (n4 + block - 1) / block;   // 16384
    int grid = 2 * blocks_per_role;                   // 32768, roles interleaved

    fused_roles_kernel<<<grid, block, 0, stream>>>(x4, w4, out4, n4);
}